// Round 1
// baseline (925.486 us; speedup 1.0000x reference)
//
#include <hip/hip_runtime.h>
#include <math.h>

#define B_ 8
#define T_ 4
#define N_ 2048
#define C_ 11
#define D_ 64
#define H_ 4
#define HD_ 16
#define K_ 16
#define BT_ (B_*T_)

__device__ __forceinline__ float softplus_f(float x) {
    return fmaxf(x, 0.f) + log1pf(expf(-fabsf(x)));
}

// ---------------- Kernel A: embedding MLP (BN folded) ----------------
__global__ __launch_bounds__(256) void k_embed(
    const float* __restrict__ x,
    const float* __restrict__ w1, const float* __restrict__ b1,
    const float* __restrict__ g1, const float* __restrict__ bb1,
    const float* __restrict__ m1, const float* __restrict__ v1,
    const float* __restrict__ w2, const float* __restrict__ b2,
    const float* __restrict__ g2, const float* __restrict__ bb2,
    const float* __restrict__ m2, const float* __restrict__ v2,
    float* __restrict__ h)
{
    __shared__ float sw1[32*C_], sb1[32], sw2[D_*32], sb2[D_];
    int t = threadIdx.x;
    if (t < 32) {
        float s = g1[t] / sqrtf(v1[t] + 1e-5f);
        sb1[t] = (b1[t] - m1[t]) * s + bb1[t];
        for (int c = 0; c < C_; ++c) sw1[t*C_+c] = w1[t*C_+c] * s;
    } else if (t >= 64 && t < 128) {
        int j = t - 64;
        float s = g2[j] / sqrtf(v2[j] + 1e-5f);
        sb2[j] = (b2[j] - m2[j]) * s + bb2[j];
        for (int c = 0; c < 32; ++c) sw2[j*32+c] = w2[j*32+c] * s;
    }
    __syncthreads();

    int node = blockIdx.x * 256 + t;
    const float* xp = x + (size_t)node * C_;
    float xin[C_];
    #pragma unroll
    for (int c = 0; c < C_; ++c) xin[c] = xp[c];

    float t1[32];
    #pragma unroll
    for (int j = 0; j < 32; ++j) {
        float a = sb1[j];
        #pragma unroll
        for (int c = 0; c < C_; ++c) a = fmaf(xin[c], sw1[j*C_+c], a);
        t1[j] = fmaxf(a, 0.f);
    }
    float* hp = h + (size_t)node * D_;
    #pragma unroll 4
    for (int j = 0; j < D_; ++j) {
        float a = sb2[j];
        #pragma unroll
        for (int c = 0; c < 32; ++c) a = fmaf(t1[c], sw2[j*32+c], a);
        hp[j] = fmaxf(a, 0.f);
    }
}

// ---------------- Kernel B: exact 16-NN (values-bubble + index recovery) ----
__global__ __launch_bounds__(256) void k_knn(const float* __restrict__ x,
                                             int* __restrict__ idx)
{
    __shared__ float2 sp[N_];
    __shared__ float  sps[N_];
    const int bt    = blockIdx.x >> 3;
    const int nbase = (blockIdx.x & 7) << 8;
    const float* xb = x + (size_t)bt * N_ * C_;
    for (int m = threadIdx.x; m < N_; m += 256) {
        float a = xb[m*C_ + 0];
        float b = xb[m*C_ + 1];
        sp[m]  = make_float2(a, b);
        sps[m] = __fmaf_rn(a, a, __fmul_rn(b, b));
    }
    __syncthreads();

    const int n = nbase + threadIdx.x;
    const float xn = sp[n].x, yn = sp[n].y;

    // Pass 1: smallest-16 VALUES of d' = |p_m|^2 - 2*(p_n . p_m)  (order == d2)
    float bd[K_];
    #pragma unroll
    for (int i = 0; i < K_; ++i) bd[i] = 3.402823466e38f;

    for (int m = 0; m < N_; ++m) {
        float2 p = sp[m];
        float t = __fmul_rn(xn, p.x);
        t = __fmaf_rn(yn, p.y, t);
        float d = __fmaf_rn(-2.f, t, sps[m]);
        if (d < bd[K_-1]) {
            float c = d;
            #pragma unroll
            for (int i = 0; i < K_; ++i) {
                float lo = fminf(bd[i], c);
                c = fmaxf(bd[i], c);
                bd[i] = lo;
            }
        }
    }
    const float d15 = bd[K_-1];

    // Pass 2: recover indices; ascending m => stable lowest-index tie-break
    int* op = idx + ((size_t)bt * N_ + n) * K_;
    int cnt = 0, c1 = 0, cs = 0;
    for (int m = 0; m < N_; ++m) {
        float2 p = sp[m];
        float t = __fmul_rn(xn, p.x);
        t = __fmaf_rn(yn, p.y, t);
        float d = __fmaf_rn(-2.f, t, sps[m]);
        bool lt = d < d15;
        bool le = d <= d15;
        if (lt) c1++;
        if (le && cnt < K_) { op[cnt] = m; cnt++; if (lt) cs++; }
    }
    if (cs != c1) {   // rare: an exact-tie displaced a strict item; redo exactly
        cnt = 0;
        for (int m = 0; m < N_ && cnt < K_; ++m) {
            float2 p = sp[m];
            float t = __fmul_rn(xn, p.x);
            t = __fmaf_rn(yn, p.y, t);
            float d = __fmaf_rn(-2.f, t, sps[m]);
            if (d < d15) { op[cnt] = m; cnt++; }
        }
        for (int m = 0; m < N_ && cnt < K_; ++m) {
            float2 p = sp[m];
            float t = __fmul_rn(xn, p.x);
            t = __fmaf_rn(yn, p.y, t);
            float d = __fmaf_rn(-2.f, t, sps[m]);
            if (d == d15) { op[cnt] = m; cnt++; }
        }
    }
}

// ---------------- Kernel C1: hw = h @ gat_W^T, s_self ----------------
__global__ __launch_bounds__(256) void k_gatw(
    const float* __restrict__ h, const float* __restrict__ gw,
    const float* __restrict__ att,
    float* __restrict__ hw, float* __restrict__ ssf)
{
    __shared__ float sw[D_*D_];
    __shared__ float sat[H_*HD_];
    int t = threadIdx.x;
    for (int i = t; i < D_*D_; i += 256) sw[i] = gw[i];
    if (t < H_*HD_) sat[t] = att[(t>>4)*(2*HD_) + (t & (HD_-1))];
    __syncthreads();

    int node = blockIdx.x * 256 + t;
    const float* hp = h + (size_t)node * D_;
    float hin[D_];
    #pragma unroll
    for (int j = 0; j < D_; j += 4) {
        float4 v = *(const float4*)(hp + j);
        hin[j] = v.x; hin[j+1] = v.y; hin[j+2] = v.z; hin[j+3] = v.w;
    }
    float* wp = hw + (size_t)node * D_;
    float ss[H_];
    #pragma unroll
    for (int hh = 0; hh < H_; ++hh) {
        ss[hh] = 0.f;
        #pragma unroll
        for (int jj = 0; jj < HD_; ++jj) {
            const int j = hh*HD_ + jj;
            float a = 0.f;
            const float4* wr = (const float4*)(&sw[j*D_]);
            #pragma unroll
            for (int c4 = 0; c4 < D_/4; ++c4) {
                float4 w4 = wr[c4];
                a = fmaf(hin[4*c4+0], w4.x, a);
                a = fmaf(hin[4*c4+1], w4.y, a);
                a = fmaf(hin[4*c4+2], w4.z, a);
                a = fmaf(hin[4*c4+3], w4.w, a);
            }
            wp[j] = a;
            ss[hh] = fmaf(a, sat[j], ss[hh]);
        }
    }
    float* sp2 = ssf + (size_t)node * H_;
    #pragma unroll
    for (int hh = 0; hh < H_; ++hh) sp2[hh] = ss[hh];
}

// ---------------- Kernel C2: GAT gather/softmax/aggregate + residual -------
__global__ __launch_bounds__(256) void k_gat(
    const float* __restrict__ hw, const float* __restrict__ ssf,
    const int* __restrict__ idx, const float* __restrict__ att,
    float* __restrict__ h /* in-out: becomes h_sp */)
{
    int t = threadIdx.x;
    int node = blockIdx.x * 64 + (t >> 2);
    int hh = t & 3;
    int bt = node >> 11;
    const int* ip = idx + (size_t)node * K_;

    float anb[HD_];
    #pragma unroll
    for (int i = 0; i < HD_; ++i) anb[i] = att[hh*(2*HD_) + HD_ + i];
    float ssv = ssf[(size_t)node*H_ + hh];
    const float* hwb = hw + ((size_t)bt * N_) * D_;

    int nb[K_];
    #pragma unroll
    for (int k = 0; k < K_; ++k) nb[k] = ip[k];

    float sc[K_];
    float mx = -3.402823466e38f;
    #pragma unroll
    for (int k = 0; k < K_; ++k) {
        const float* vp = hwb + (size_t)nb[k]*D_ + hh*HD_;
        float a = 0.f;
        #pragma unroll
        for (int i = 0; i < HD_; i += 4) {
            float4 v = *(const float4*)(vp + i);
            a = fmaf(v.x, anb[i],   a);
            a = fmaf(v.y, anb[i+1], a);
            a = fmaf(v.z, anb[i+2], a);
            a = fmaf(v.w, anb[i+3], a);
        }
        float s = ssv + a;
        s = (s >= 0.f) ? s : 0.2f * s;   // leaky_relu(0.2)
        sc[k] = s;
        mx = fmaxf(mx, s);
    }
    float den = 0.f;
    #pragma unroll
    for (int k = 0; k < K_; ++k) { sc[k] = __expf(sc[k] - mx); den += sc[k]; }
    float inv = 1.f / den;

    float acc[HD_];
    #pragma unroll
    for (int i = 0; i < HD_; ++i) acc[i] = 0.f;
    #pragma unroll
    for (int k = 0; k < K_; ++k) {
        float al = sc[k] * inv;
        const float* vp = hwb + (size_t)nb[k]*D_ + hh*HD_;
        #pragma unroll
        for (int i = 0; i < HD_; i += 4) {
            float4 v = *(const float4*)(vp + i);
            acc[i]   = fmaf(v.x, al, acc[i]);
            acc[i+1] = fmaf(v.y, al, acc[i+1]);
            acc[i+2] = fmaf(v.z, al, acc[i+2]);
            acc[i+3] = fmaf(v.w, al, acc[i+3]);
        }
    }
    float* hp = h + (size_t)node*D_ + hh*HD_;
    #pragma unroll
    for (int i = 0; i < HD_; ++i) hp[i] = fmaxf(acc[i] + hp[i], 0.f);
}

// ---------------- Kernel D1: Q and KV projections ----------------
__global__ __launch_bounds__(256) void k_qkv(
    const float* __restrict__ hsp,
    const float* __restrict__ qw, const float* __restrict__ qb,
    const float* __restrict__ kw, const float* __restrict__ kb,
    float* __restrict__ q, float* __restrict__ kv)
{
    __shared__ float s_qw[D_*D_], s_kw[D_*D_], s_qb[D_], s_kb[D_];
    int t = threadIdx.x;
    for (int i = t; i < D_*D_; i += 256) { s_qw[i] = qw[i]; s_kw[i] = kw[i]; }
    if (t < D_) { s_qb[t] = qb[t]; s_kb[t] = kb[t]; }
    __syncthreads();

    int r = blockIdx.x * 256 + t;
    const float* in; float* outp; const float* W; const float* bb;
    if (r < BT_*N_) {
        int bt = r >> 11; int n = r & (N_-1);
        int b = bt >> 2, tt = bt & 3;
        in = hsp + (size_t)r * D_;
        outp = kv + (((size_t)(b*N_ + n))*T_ + tt) * D_;
        W = s_kw; bb = s_kb;
    } else {
        int rr = r - BT_*N_;
        int b = rr >> 11, n = rr & (N_-1);
        in = hsp + ((size_t)(b*T_ + (T_-1))*N_ + n) * D_;
        outp = q + (size_t)rr * D_;
        W = s_qw; bb = s_qb;
    }
    float xin[D_];
    #pragma unroll
    for (int j = 0; j < D_; j += 4) {
        float4 v = *(const float4*)(in + j);
        xin[j] = v.x; xin[j+1] = v.y; xin[j+2] = v.z; xin[j+3] = v.w;
    }
    #pragma unroll 4
    for (int j = 0; j < D_; ++j) {
        float a = bb[j];
        const float4* wr = (const float4*)(&W[j*D_]);
        #pragma unroll
        for (int c4 = 0; c4 < D_/4; ++c4) {
            float4 w4 = wr[c4];
            a = fmaf(xin[4*c4+0], w4.x, a);
            a = fmaf(xin[4*c4+1], w4.y, a);
            a = fmaf(xin[4*c4+2], w4.z, a);
            a = fmaf(xin[4*c4+3], w4.w, a);
        }
        outp[j] = a;
    }
}

// ---------------- Kernel D2: temporal attention + output heads -------------
__global__ __launch_bounds__(64) void k_head(
    const float* __restrict__ q, const float* __restrict__ kv,
    const float* __restrict__ lw1, const float* __restrict__ lb1,
    const float* __restrict__ lw2, const float* __restrict__ lb2,
    const float* __restrict__ rw1, const float* __restrict__ rb1,
    const float* __restrict__ rw2, const float* __restrict__ rb2,
    float* __restrict__ out)
{
    __shared__ float sl1[32*D_], sr1[32*D_], sl2[4*32], sr2[4*32];
    __shared__ float slb1[32], srb1[32], slb2[4], srb2[4];
    int t = threadIdx.x;
    for (int i = t; i < 32*D_; i += 64) { sl1[i] = lw1[i]; sr1[i] = rw1[i]; }
    for (int i = t; i < 128; i += 64)   { sl2[i] = lw2[i]; sr2[i] = rw2[i]; }
    if (t < 32) { slb1[t] = lb1[t]; srb1[t] = rb1[t]; }
    if (t < 4)  { slb2[t] = lb2[t]; srb2[t] = rb2[t]; }
    __syncthreads();

    int rn = blockIdx.x * 64 + t;           // = b*N + n
    const float* qp = q + (size_t)rn * D_;
    const float* kp = kv + (size_t)rn * T_ * D_;

    float qv[D_];
    #pragma unroll
    for (int j = 0; j < D_; j += 4) {
        float4 v = *(const float4*)(qp + j);
        qv[j] = v.x; qv[j+1] = v.y; qv[j+2] = v.z; qv[j+3] = v.w;
    }
    float scv[T_];
    #pragma unroll
    for (int tt = 0; tt < T_; ++tt) {
        float a = 0.f;
        const float4* kr = (const float4*)(kp + tt*D_);
        #pragma unroll
        for (int c4 = 0; c4 < D_/4; ++c4) {
            float4 v = kr[c4];
            a = fmaf(qv[4*c4+0], v.x, a);
            a = fmaf(qv[4*c4+1], v.y, a);
            a = fmaf(qv[4*c4+2], v.z, a);
            a = fmaf(qv[4*c4+3], v.w, a);
        }
        scv[tt] = a * 0.125f;
    }
    float mx = fmaxf(fmaxf(scv[0], scv[1]), fmaxf(scv[2], scv[3]));
    float wsum = 0.f;
    #pragma unroll
    for (int tt = 0; tt < T_; ++tt) { scv[tt] = expf(scv[tt] - mx); wsum += scv[tt]; }
    float winv = 1.f / wsum;

    float hf[D_];
    #pragma unroll
    for (int j = 0; j < D_; ++j) hf[j] = 0.f;
    #pragma unroll
    for (int tt = 0; tt < T_; ++tt) {
        float w = scv[tt] * winv;
        const float4* kr = (const float4*)(kp + tt*D_);
        #pragma unroll
        for (int c4 = 0; c4 < D_/4; ++c4) {
            float4 v = kr[c4];
            hf[4*c4+0] = fmaf(v.x, w, hf[4*c4+0]);
            hf[4*c4+1] = fmaf(v.y, w, hf[4*c4+1]);
            hf[4*c4+2] = fmaf(v.z, w, hf[4*c4+2]);
            hf[4*c4+3] = fmaf(v.w, w, hf[4*c4+3]);
        }
    }
    // lidar head
    float ol0 = slb2[0], ol1 = slb2[1], ol2 = slb2[2], ol3 = slb2[3];
    #pragma unroll 2
    for (int j = 0; j < 32; ++j) {
        float a = slb1[j];
        const float4* wr = (const float4*)(&sl1[j*D_]);
        #pragma unroll
        for (int c4 = 0; c4 < D_/4; ++c4) {
            float4 v = wr[c4];
            a = fmaf(hf[4*c4+0], v.x, a);
            a = fmaf(hf[4*c4+1], v.y, a);
            a = fmaf(hf[4*c4+2], v.z, a);
            a = fmaf(hf[4*c4+3], v.w, a);
        }
        a = fmaxf(a, 0.f);
        ol0 = fmaf(a, sl2[0*32+j], ol0);
        ol1 = fmaf(a, sl2[1*32+j], ol1);
        ol2 = fmaf(a, sl2[2*32+j], ol2);
        ol3 = fmaf(a, sl2[3*32+j], ol3);
    }
    // radar head
    float or0 = srb2[0], or1 = srb2[1], or2 = srb2[2], or3 = srb2[3];
    #pragma unroll 2
    for (int j = 0; j < 32; ++j) {
        float a = srb1[j];
        const float4* wr = (const float4*)(&sr1[j*D_]);
        #pragma unroll
        for (int c4 = 0; c4 < D_/4; ++c4) {
            float4 v = wr[c4];
            a = fmaf(hf[4*c4+0], v.x, a);
            a = fmaf(hf[4*c4+1], v.y, a);
            a = fmaf(hf[4*c4+2], v.z, a);
            a = fmaf(hf[4*c4+3], v.w, a);
        }
        a = fmaxf(a, 0.f);
        or0 = fmaf(a, sr2[0*32+j], or0);
        or1 = fmaf(a, sr2[1*32+j], or1);
        or2 = fmaf(a, sr2[2*32+j], or2);
        or3 = fmaf(a, sr2[3*32+j], or3);
    }
    const int NB = B_ * N_;                  // 16384
    out[0*2*NB + rn*2 + 0] = ol0;
    out[0*2*NB + rn*2 + 1] = ol1;
    out[1*2*NB + rn*2 + 0] = softplus_f(ol2) + 1e-6f;
    out[1*2*NB + rn*2 + 1] = softplus_f(ol3) + 1e-6f;
    out[2*2*NB + rn*2 + 0] = or0;
    out[2*2*NB + rn*2 + 1] = or1;
    out[3*2*NB + rn*2 + 0] = softplus_f(or2) + 1e-6f;
    out[3*2*NB + rn*2 + 1] = softplus_f(or3) + 1e-6f;
}

// ---------------- launcher ----------------
extern "C" void kernel_launch(void* const* d_in, const int* in_sizes, int n_in,
                              void* d_out, int out_size, void* d_ws, size_t ws_size,
                              hipStream_t stream)
{
    const float* x   = (const float*)d_in[0];
    const float* ew1 = (const float*)d_in[1];
    const float* eb1 = (const float*)d_in[2];
    const float* g1  = (const float*)d_in[3];
    const float* bb1 = (const float*)d_in[4];
    const float* m1  = (const float*)d_in[5];
    const float* v1  = (const float*)d_in[6];
    const float* ew2 = (const float*)d_in[7];
    const float* eb2 = (const float*)d_in[8];
    const float* g2  = (const float*)d_in[9];
    const float* bb2 = (const float*)d_in[10];
    const float* m2  = (const float*)d_in[11];
    const float* v2  = (const float*)d_in[12];
    const float* gw  = (const float*)d_in[13];
    const float* att = (const float*)d_in[14];
    const float* qw  = (const float*)d_in[15];
    const float* qb  = (const float*)d_in[16];
    const float* kw  = (const float*)d_in[17];
    const float* kb  = (const float*)d_in[18];
    const float* lw1 = (const float*)d_in[19];
    const float* lb1 = (const float*)d_in[20];
    const float* lw2 = (const float*)d_in[21];
    const float* lb2 = (const float*)d_in[22];
    const float* rw1 = (const float*)d_in[23];
    const float* rb1 = (const float*)d_in[24];
    const float* rw2 = (const float*)d_in[25];
    const float* rb2 = (const float*)d_in[26];
    float* out = (float*)d_out;

    float* h   = (float*)d_ws;                               // BT*N*64
    float* hw  = h   + (size_t)BT_*N_*D_;                    // BT*N*64
    float* ssf = hw  + (size_t)BT_*N_*D_;                    // BT*N*4
    int*   idx = (int*)(ssf + (size_t)BT_*N_*H_);            // BT*N*16
    float* q   = (float*)(idx + (size_t)BT_*N_*K_);          // B*N*64
    float* kv  = hw;   // reuse hw after GAT aggregation

    k_embed<<<BT_*N_/256, 256, 0, stream>>>(x, ew1, eb1, g1, bb1, m1, v1,
                                            ew2, eb2, g2, bb2, m2, v2, h);
    k_knn<<<BT_*(N_/256), 256, 0, stream>>>(x, idx);
    k_gatw<<<BT_*N_/256, 256, 0, stream>>>(h, gw, att, hw, ssf);
    k_gat<<<(BT_*N_*H_)/256, 256, 0, stream>>>(hw, ssf, idx, att, h);
    k_qkv<<<(BT_*N_ + B_*N_)/256, 256, 0, stream>>>(h, qw, qb, kw, kb, q, kv);
    k_head<<<(B_*N_)/64, 64, 0, stream>>>(q, kv, lw1, lb1, lw2, lb2,
                                          rw1, rb1, rw2, rb2, out);
}

// Round 2
// 388.131 us; speedup vs baseline: 2.3845x; 2.3845x over previous
//
#include <hip/hip_runtime.h>
#include <math.h>

#define B_ 8
#define T_ 4
#define N_ 2048
#define C_ 11
#define D_ 64
#define H_ 4
#define HD_ 16
#define K_ 16
#define BT_ (B_*T_)

__device__ __forceinline__ float softplus_f(float x) {
    return fmaxf(x, 0.f) + log1pf(expf(-fabsf(x)));
}

// ---------------- Kernel A: embedding MLP (BN folded) + pos pack ----------
__global__ __launch_bounds__(256) void k_embed(
    const float* __restrict__ x,
    const float* __restrict__ w1, const float* __restrict__ b1,
    const float* __restrict__ g1, const float* __restrict__ bb1,
    const float* __restrict__ m1, const float* __restrict__ v1,
    const float* __restrict__ w2, const float* __restrict__ b2,
    const float* __restrict__ g2, const float* __restrict__ bb2,
    const float* __restrict__ m2, const float* __restrict__ v2,
    float* __restrict__ h, float2* __restrict__ pos)
{
    __shared__ float sw1[32*C_], sb1[32], sw2[D_*32], sb2[D_];
    int t = threadIdx.x;
    if (t < 32) {
        float s = g1[t] / sqrtf(v1[t] + 1e-5f);
        sb1[t] = (b1[t] - m1[t]) * s + bb1[t];
        for (int c = 0; c < C_; ++c) sw1[t*C_+c] = w1[t*C_+c] * s;
    } else if (t >= 64 && t < 128) {
        int j = t - 64;
        float s = g2[j] / sqrtf(v2[j] + 1e-5f);
        sb2[j] = (b2[j] - m2[j]) * s + bb2[j];
        for (int c = 0; c < 32; ++c) sw2[j*32+c] = w2[j*32+c] * s;
    }
    __syncthreads();

    int node = blockIdx.x * 256 + t;
    const float* xp = x + (size_t)node * C_;
    float xin[C_];
    #pragma unroll
    for (int c = 0; c < C_; ++c) xin[c] = xp[c];
    pos[node] = make_float2(xin[0], xin[1]);

    float t1[32];
    #pragma unroll
    for (int j = 0; j < 32; ++j) {
        float a = sb1[j];
        #pragma unroll
        for (int c = 0; c < C_; ++c) a = fmaf(xin[c], sw1[j*C_+c], a);
        t1[j] = fmaxf(a, 0.f);
    }
    float* hp = h + (size_t)node * D_;
    #pragma unroll 4
    for (int j = 0; j < D_; ++j) {
        float a = sb2[j];
        #pragma unroll
        for (int c = 0; c < 32; ++c) a = fmaf(t1[c], sw2[j*32+c], a);
        hp[j] = fmaxf(a, 0.f);
    }
}

// ---------------- Kernel B: exact 16-NN, G=8 threads per query ----------
// thread g of a query scans candidates m === g (mod 8); local sorted top-16
// values; 3-stage shfl_xor bitonic merge -> global top-16 values; recovery
// pass compacts indices via LDS atomic (order-free: softmax over k is
// permutation-invariant). Distance bits identical to the round-1 kernel.
__global__ __launch_bounds__(256) void k_knn(const float2* __restrict__ pos,
                                             int* __restrict__ idx)
{
    __shared__ float2 sp[N_];
    __shared__ int scnt[32];
    const int bt    = blockIdx.x >> 6;          // 64 blocks per bt
    const int qbase = (blockIdx.x & 63) << 5;   // 32 queries per block
    const float2* pb = pos + (size_t)bt * N_;
    for (int m = threadIdx.x; m < N_; m += 256) sp[m] = pb[m];
    if (threadIdx.x < 32) scnt[threadIdx.x] = 0;
    __syncthreads();

    const int q = threadIdx.x >> 3;
    const int g = threadIdx.x & 7;
    const int n = qbase + q;
    const float xn = sp[n].x, yn = sp[n].y;

    float bd[K_];
    #pragma unroll
    for (int i = 0; i < K_; ++i) bd[i] = 3.402823466e38f;

    // Pass 1: per-thread top-16 values over 256 strided candidates
    for (int i = 0; i < N_/32; ++i) {
        float d[4];
        #pragma unroll
        for (int j = 0; j < 4; ++j) {
            float2 p = sp[32*i + 8*j + g];
            float sps = __fmaf_rn(p.x, p.x, __fmul_rn(p.y, p.y));
            float t = __fmul_rn(xn, p.x);
            t = __fmaf_rn(yn, p.y, t);
            d[j] = __fmaf_rn(-2.f, t, sps);
        }
        float dmin = fminf(fminf(d[0], d[1]), fminf(d[2], d[3]));
        if (dmin < bd[K_-1]) {
            #pragma unroll
            for (int j = 0; j < 4; ++j) {
                if (d[j] < bd[K_-1]) {
                    float c = d[j];
                    #pragma unroll
                    for (int s = 0; s < K_; ++s) {
                        float lo = fminf(bd[s], c);
                        c = fmaxf(bd[s], c);
                        bd[s] = lo;
                    }
                }
            }
        }
    }

    // Merge the 8 sorted lists (values): 3 stages of bitonic merge-16
    #pragma unroll
    for (int st = 1; st <= 4; st <<= 1) {
        float pr[K_];
        #pragma unroll
        for (int i = 0; i < K_; ++i) pr[i] = __shfl_xor(bd[K_-1-i], st, 64);
        #pragma unroll
        for (int i = 0; i < K_; ++i) bd[i] = fminf(bd[i], pr[i]);
        #pragma unroll
        for (int dd = 8; dd >= 1; dd >>= 1) {
            #pragma unroll
            for (int i = 0; i < K_; ++i) {
                if ((i & dd) == 0) {
                    float lo = fminf(bd[i], bd[i+dd]);
                    float hi = fmaxf(bd[i], bd[i+dd]);
                    bd[i] = lo; bd[i+dd] = hi;
                }
            }
        }
    }
    const float d15 = bd[K_-1];

    // Pass 2: recover indices (own stride only), compact via LDS atomic
    int* op = idx + ((size_t)bt * N_ + n) * K_;
    for (int i = 0; i < N_/32; ++i) {
        float d[4];
        #pragma unroll
        for (int j = 0; j < 4; ++j) {
            float2 p = sp[32*i + 8*j + g];
            float sps = __fmaf_rn(p.x, p.x, __fmul_rn(p.y, p.y));
            float t = __fmul_rn(xn, p.x);
            t = __fmaf_rn(yn, p.y, t);
            d[j] = __fmaf_rn(-2.f, t, sps);
        }
        float dmin = fminf(fminf(d[0], d[1]), fminf(d[2], d[3]));
        if (dmin <= d15) {
            #pragma unroll
            for (int j = 0; j < 4; ++j) {
                if (d[j] <= d15) {
                    int pos_ = atomicAdd(&scnt[q], 1);
                    if (pos_ < K_) op[pos_] = 32*i + 8*j + g;
                }
            }
        }
    }
}

// ---------------- Kernel C1: hw = h @ gat_W^T, s_self ----------------
__global__ __launch_bounds__(256) void k_gatw(
    const float* __restrict__ h, const float* __restrict__ gw,
    const float* __restrict__ att,
    float* __restrict__ hw, float* __restrict__ ssf)
{
    __shared__ float sw[D_*D_];
    __shared__ float sat[H_*HD_];
    int t = threadIdx.x;
    for (int i = t; i < D_*D_; i += 256) sw[i] = gw[i];
    if (t < H_*HD_) sat[t] = att[(t>>4)*(2*HD_) + (t & (HD_-1))];
    __syncthreads();

    int node = blockIdx.x * 256 + t;
    const float* hp = h + (size_t)node * D_;
    float hin[D_];
    #pragma unroll
    for (int j = 0; j < D_; j += 4) {
        float4 v = *(const float4*)(hp + j);
        hin[j] = v.x; hin[j+1] = v.y; hin[j+2] = v.z; hin[j+3] = v.w;
    }
    float* wp = hw + (size_t)node * D_;
    float ss[H_];
    #pragma unroll
    for (int hh = 0; hh < H_; ++hh) {
        ss[hh] = 0.f;
        #pragma unroll
        for (int jj = 0; jj < HD_; ++jj) {
            const int j = hh*HD_ + jj;
            float a = 0.f;
            const float4* wr = (const float4*)(&sw[j*D_]);
            #pragma unroll
            for (int c4 = 0; c4 < D_/4; ++c4) {
                float4 w4 = wr[c4];
                a = fmaf(hin[4*c4+0], w4.x, a);
                a = fmaf(hin[4*c4+1], w4.y, a);
                a = fmaf(hin[4*c4+2], w4.z, a);
                a = fmaf(hin[4*c4+3], w4.w, a);
            }
            wp[j] = a;
            ss[hh] = fmaf(a, sat[j], ss[hh]);
        }
    }
    float* sp2 = ssf + (size_t)node * H_;
    #pragma unroll
    for (int hh = 0; hh < H_; ++hh) sp2[hh] = ss[hh];
}

// ---------------- Kernel C2: GAT gather/softmax/aggregate + residual -------
__global__ __launch_bounds__(256) void k_gat(
    const float* __restrict__ hw, const float* __restrict__ ssf,
    const int* __restrict__ idx, const float* __restrict__ att,
    float* __restrict__ h /* in-out: becomes h_sp */)
{
    int t = threadIdx.x;
    int node = blockIdx.x * 64 + (t >> 2);
    int hh = t & 3;
    int bt = node >> 11;
    const int* ip = idx + (size_t)node * K_;

    float anb[HD_];
    #pragma unroll
    for (int i = 0; i < HD_; ++i) anb[i] = att[hh*(2*HD_) + HD_ + i];
    float ssv = ssf[(size_t)node*H_ + hh];
    const float* hwb = hw + ((size_t)bt * N_) * D_;

    int nb[K_];
    #pragma unroll
    for (int k = 0; k < K_; ++k) nb[k] = ip[k];

    float sc[K_];
    float mx = -3.402823466e38f;
    #pragma unroll
    for (int k = 0; k < K_; ++k) {
        const float* vp = hwb + (size_t)nb[k]*D_ + hh*HD_;
        float a = 0.f;
        #pragma unroll
        for (int i = 0; i < HD_; i += 4) {
            float4 v = *(const float4*)(vp + i);
            a = fmaf(v.x, anb[i],   a);
            a = fmaf(v.y, anb[i+1], a);
            a = fmaf(v.z, anb[i+2], a);
            a = fmaf(v.w, anb[i+3], a);
        }
        float s = ssv + a;
        s = (s >= 0.f) ? s : 0.2f * s;   // leaky_relu(0.2)
        sc[k] = s;
        mx = fmaxf(mx, s);
    }
    float den = 0.f;
    #pragma unroll
    for (int k = 0; k < K_; ++k) { sc[k] = __expf(sc[k] - mx); den += sc[k]; }
    float inv = 1.f / den;

    float acc[HD_];
    #pragma unroll
    for (int i = 0; i < HD_; ++i) acc[i] = 0.f;
    #pragma unroll
    for (int k = 0; k < K_; ++k) {
        float al = sc[k] * inv;
        const float* vp = hwb + (size_t)nb[k]*D_ + hh*HD_;
        #pragma unroll
        for (int i = 0; i < HD_; i += 4) {
            float4 v = *(const float4*)(vp + i);
            acc[i]   = fmaf(v.x, al, acc[i]);
            acc[i+1] = fmaf(v.y, al, acc[i+1]);
            acc[i+2] = fmaf(v.z, al, acc[i+2]);
            acc[i+3] = fmaf(v.w, al, acc[i+3]);
        }
    }
    float* hp = h + (size_t)node*D_ + hh*HD_;
    #pragma unroll
    for (int i = 0; i < HD_; ++i) hp[i] = fmaxf(acc[i] + hp[i], 0.f);
}

// ---------------- Kernel D1: Q and KV projections ----------------
__global__ __launch_bounds__(256) void k_qkv(
    const float* __restrict__ hsp,
    const float* __restrict__ qw, const float* __restrict__ qb,
    const float* __restrict__ kw, const float* __restrict__ kb,
    float* __restrict__ q, float* __restrict__ kv)
{
    __shared__ float s_qw[D_*D_], s_kw[D_*D_], s_qb[D_], s_kb[D_];
    int t = threadIdx.x;
    for (int i = t; i < D_*D_; i += 256) { s_qw[i] = qw[i]; s_kw[i] = kw[i]; }
    if (t < D_) { s_qb[t] = qb[t]; s_kb[t] = kb[t]; }
    __syncthreads();

    int r = blockIdx.x * 256 + t;
    const float* in; float* outp; const float* W; const float* bb;
    if (r < BT_*N_) {
        int bt = r >> 11; int n = r & (N_-1);
        int b = bt >> 2, tt = bt & 3;
        in = hsp + (size_t)r * D_;
        outp = kv + (((size_t)(b*N_ + n))*T_ + tt) * D_;
        W = s_kw; bb = s_kb;
    } else {
        int rr = r - BT_*N_;
        int b = rr >> 11, n = rr & (N_-1);
        in = hsp + ((size_t)(b*T_ + (T_-1))*N_ + n) * D_;
        outp = q + (size_t)rr * D_;
        W = s_qw; bb = s_qb;
    }
    float xin[D_];
    #pragma unroll
    for (int j = 0; j < D_; j += 4) {
        float4 v = *(const float4*)(in + j);
        xin[j] = v.x; xin[j+1] = v.y; xin[j+2] = v.z; xin[j+3] = v.w;
    }
    #pragma unroll 4
    for (int j = 0; j < D_; ++j) {
        float a = bb[j];
        const float4* wr = (const float4*)(&W[j*D_]);
        #pragma unroll
        for (int c4 = 0; c4 < D_/4; ++c4) {
            float4 w4 = wr[c4];
            a = fmaf(xin[4*c4+0], w4.x, a);
            a = fmaf(xin[4*c4+1], w4.y, a);
            a = fmaf(xin[4*c4+2], w4.z, a);
            a = fmaf(xin[4*c4+3], w4.w, a);
        }
        outp[j] = a;
    }
}

// ---------------- Kernel D2: temporal attention + output heads -------------
__global__ __launch_bounds__(64) void k_head(
    const float* __restrict__ q, const float* __restrict__ kv,
    const float* __restrict__ lw1, const float* __restrict__ lb1,
    const float* __restrict__ lw2, const float* __restrict__ lb2,
    const float* __restrict__ rw1, const float* __restrict__ rb1,
    const float* __restrict__ rw2, const float* __restrict__ rb2,
    float* __restrict__ out)
{
    __shared__ float sl1[32*D_], sr1[32*D_], sl2[4*32], sr2[4*32];
    __shared__ float slb1[32], srb1[32], slb2[4], srb2[4];
    int t = threadIdx.x;
    for (int i = t; i < 32*D_; i += 64) { sl1[i] = lw1[i]; sr1[i] = rw1[i]; }
    for (int i = t; i < 128; i += 64)   { sl2[i] = lw2[i]; sr2[i] = rw2[i]; }
    if (t < 32) { slb1[t] = lb1[t]; srb1[t] = rb1[t]; }
    if (t < 4)  { slb2[t] = lb2[t]; srb2[t] = rb2[t]; }
    __syncthreads();

    int rn = blockIdx.x * 64 + t;           // = b*N + n
    const float* qp = q + (size_t)rn * D_;
    const float* kp = kv + (size_t)rn * T_ * D_;

    float qv[D_];
    #pragma unroll
    for (int j = 0; j < D_; j += 4) {
        float4 v = *(const float4*)(qp + j);
        qv[j] = v.x; qv[j+1] = v.y; qv[j+2] = v.z; qv[j+3] = v.w;
    }
    float scv[T_];
    #pragma unroll
    for (int tt = 0; tt < T_; ++tt) {
        float a = 0.f;
        const float4* kr = (const float4*)(kp + tt*D_);
        #pragma unroll
        for (int c4 = 0; c4 < D_/4; ++c4) {
            float4 v = kr[c4];
            a = fmaf(qv[4*c4+0], v.x, a);
            a = fmaf(qv[4*c4+1], v.y, a);
            a = fmaf(qv[4*c4+2], v.z, a);
            a = fmaf(qv[4*c4+3], v.w, a);
        }
        scv[tt] = a * 0.125f;
    }
    float mx = fmaxf(fmaxf(scv[0], scv[1]), fmaxf(scv[2], scv[3]));
    float wsum = 0.f;
    #pragma unroll
    for (int tt = 0; tt < T_; ++tt) { scv[tt] = expf(scv[tt] - mx); wsum += scv[tt]; }
    float winv = 1.f / wsum;

    float hf[D_];
    #pragma unroll
    for (int j = 0; j < D_; ++j) hf[j] = 0.f;
    #pragma unroll
    for (int tt = 0; tt < T_; ++tt) {
        float w = scv[tt] * winv;
        const float4* kr = (const float4*)(kp + tt*D_);
        #pragma unroll
        for (int c4 = 0; c4 < D_/4; ++c4) {
            float4 v = kr[c4];
            hf[4*c4+0] = fmaf(v.x, w, hf[4*c4+0]);
            hf[4*c4+1] = fmaf(v.y, w, hf[4*c4+1]);
            hf[4*c4+2] = fmaf(v.z, w, hf[4*c4+2]);
            hf[4*c4+3] = fmaf(v.w, w, hf[4*c4+3]);
        }
    }
    // lidar head
    float ol0 = slb2[0], ol1 = slb2[1], ol2 = slb2[2], ol3 = slb2[3];
    #pragma unroll 2
    for (int j = 0; j < 32; ++j) {
        float a = slb1[j];
        const float4* wr = (const float4*)(&sl1[j*D_]);
        #pragma unroll
        for (int c4 = 0; c4 < D_/4; ++c4) {
            float4 v = wr[c4];
            a = fmaf(hf[4*c4+0], v.x, a);
            a = fmaf(hf[4*c4+1], v.y, a);
            a = fmaf(hf[4*c4+2], v.z, a);
            a = fmaf(hf[4*c4+3], v.w, a);
        }
        a = fmaxf(a, 0.f);
        ol0 = fmaf(a, sl2[0*32+j], ol0);
        ol1 = fmaf(a, sl2[1*32+j], ol1);
        ol2 = fmaf(a, sl2[2*32+j], ol2);
        ol3 = fmaf(a, sl2[3*32+j], ol3);
    }
    // radar head
    float or0 = srb2[0], or1 = srb2[1], or2 = srb2[2], or3 = srb2[3];
    #pragma unroll 2
    for (int j = 0; j < 32; ++j) {
        float a = srb1[j];
        const float4* wr = (const float4*)(&sr1[j*D_]);
        #pragma unroll
        for (int c4 = 0; c4 < D_/4; ++c4) {
            float4 v = wr[c4];
            a = fmaf(hf[4*c4+0], v.x, a);
            a = fmaf(hf[4*c4+1], v.y, a);
            a = fmaf(hf[4*c4+2], v.z, a);
            a = fmaf(hf[4*c4+3], v.w, a);
        }
        a = fmaxf(a, 0.f);
        or0 = fmaf(a, sr2[0*32+j], or0);
        or1 = fmaf(a, sr2[1*32+j], or1);
        or2 = fmaf(a, sr2[2*32+j], or2);
        or3 = fmaf(a, sr2[3*32+j], or3);
    }
    const int NB = B_ * N_;                  // 16384
    out[0*2*NB + rn*2 + 0] = ol0;
    out[0*2*NB + rn*2 + 1] = ol1;
    out[1*2*NB + rn*2 + 0] = softplus_f(ol2) + 1e-6f;
    out[1*2*NB + rn*2 + 1] = softplus_f(ol3) + 1e-6f;
    out[2*2*NB + rn*2 + 0] = or0;
    out[2*2*NB + rn*2 + 1] = or1;
    out[3*2*NB + rn*2 + 0] = softplus_f(or2) + 1e-6f;
    out[3*2*NB + rn*2 + 1] = softplus_f(or3) + 1e-6f;
}

// ---------------- launcher ----------------
extern "C" void kernel_launch(void* const* d_in, const int* in_sizes, int n_in,
                              void* d_out, int out_size, void* d_ws, size_t ws_size,
                              hipStream_t stream)
{
    const float* x   = (const float*)d_in[0];
    const float* ew1 = (const float*)d_in[1];
    const float* eb1 = (const float*)d_in[2];
    const float* g1  = (const float*)d_in[3];
    const float* bb1 = (const float*)d_in[4];
    const float* m1  = (const float*)d_in[5];
    const float* v1  = (const float*)d_in[6];
    const float* ew2 = (const float*)d_in[7];
    const float* eb2 = (const float*)d_in[8];
    const float* g2  = (const float*)d_in[9];
    const float* bb2 = (const float*)d_in[10];
    const float* m2  = (const float*)d_in[11];
    const float* v2  = (const float*)d_in[12];
    const float* gw  = (const float*)d_in[13];
    const float* att = (const float*)d_in[14];
    const float* qw  = (const float*)d_in[15];
    const float* qb  = (const float*)d_in[16];
    const float* kw  = (const float*)d_in[17];
    const float* kb  = (const float*)d_in[18];
    const float* lw1 = (const float*)d_in[19];
    const float* lb1 = (const float*)d_in[20];
    const float* lw2 = (const float*)d_in[21];
    const float* lb2 = (const float*)d_in[22];
    const float* rw1 = (const float*)d_in[23];
    const float* rb1 = (const float*)d_in[24];
    const float* rw2 = (const float*)d_in[25];
    const float* rb2 = (const float*)d_in[26];
    float* out = (float*)d_out;

    float* h   = (float*)d_ws;                               // BT*N*64
    float* hw  = h   + (size_t)BT_*N_*D_;                    // BT*N*64
    float* ssf = hw  + (size_t)BT_*N_*D_;                    // BT*N*4
    int*   idx = (int*)(ssf + (size_t)BT_*N_*H_);            // BT*N*16
    float* q   = (float*)(idx + (size_t)BT_*N_*K_);          // B*N*64
    float* kv  = hw;             // reuse hw after GAT aggregation
    float2* pos = (float2*)q;    // overlap: pos dead before k_qkv writes q

    k_embed<<<BT_*N_/256, 256, 0, stream>>>(x, ew1, eb1, g1, bb1, m1, v1,
                                            ew2, eb2, g2, bb2, m2, v2, h, pos);
    k_knn<<<BT_*(N_/32), 256, 0, stream>>>(pos, idx);
    k_gatw<<<BT_*N_/256, 256, 0, stream>>>(h, gw, att, hw, ssf);
    k_gat<<<(BT_*N_*H_)/256, 256, 0, stream>>>(hw, ssf, idx, att, h);
    k_qkv<<<(BT_*N_ + B_*N_)/256, 256, 0, stream>>>(h, qw, qb, kw, kb, q, kv);
    k_head<<<(B_*N_)/64, 64, 0, stream>>>(q, kv, lw1, lb1, lw2, lb2,
                                          rw1, rb1, rw2, rb2, out);
}

// Round 3
// 274.143 us; speedup vs baseline: 3.3759x; 1.4158x over previous
//
#include <hip/hip_runtime.h>
#include <math.h>

#define B_ 8
#define T_ 4
#define N_ 2048
#define C_ 11
#define D_ 64
#define H_ 4
#define HD_ 16
#define K_ 16
#define BT_ (B_*T_)

__device__ __forceinline__ float softplus_f(float x) {
    return fmaxf(x, 0.f) + log1pf(expf(-fabsf(x)));
}

// ---------------- Kernel A: embedding MLP (BN folded) + pos pack ----------
__global__ __launch_bounds__(256) void k_embed(
    const float* __restrict__ x,
    const float* __restrict__ w1, const float* __restrict__ b1,
    const float* __restrict__ g1, const float* __restrict__ bb1,
    const float* __restrict__ m1, const float* __restrict__ v1,
    const float* __restrict__ w2, const float* __restrict__ b2,
    const float* __restrict__ g2, const float* __restrict__ bb2,
    const float* __restrict__ m2, const float* __restrict__ v2,
    float* __restrict__ h, float2* __restrict__ pos)
{
    __shared__ float sw1[32*C_], sb1[32], sw2[D_*32], sb2[D_];
    int t = threadIdx.x;
    if (t < 32) {
        float s = g1[t] / sqrtf(v1[t] + 1e-5f);
        sb1[t] = (b1[t] - m1[t]) * s + bb1[t];
        for (int c = 0; c < C_; ++c) sw1[t*C_+c] = w1[t*C_+c] * s;
    } else if (t >= 64 && t < 128) {
        int j = t - 64;
        float s = g2[j] / sqrtf(v2[j] + 1e-5f);
        sb2[j] = (b2[j] - m2[j]) * s + bb2[j];
        for (int c = 0; c < 32; ++c) sw2[j*32+c] = w2[j*32+c] * s;
    }
    __syncthreads();

    int node = blockIdx.x * 256 + t;
    const float* xp = x + (size_t)node * C_;
    float xin[C_];
    #pragma unroll
    for (int c = 0; c < C_; ++c) xin[c] = xp[c];
    pos[node] = make_float2(xin[0], xin[1]);

    float t1[32];
    #pragma unroll
    for (int j = 0; j < 32; ++j) {
        float a = sb1[j];
        #pragma unroll
        for (int c = 0; c < C_; ++c) a = fmaf(xin[c], sw1[j*C_+c], a);
        t1[j] = fmaxf(a, 0.f);
    }
    float* hp = h + (size_t)node * D_;
    #pragma unroll 4
    for (int j = 0; j < D_; ++j) {
        float a = sb2[j];
        #pragma unroll
        for (int c = 0; c < 32; ++c) a = fmaf(t1[c], sw2[j*32+c], a);
        hp[j] = fmaxf(a, 0.f);
    }
}

// ---------------- Kernel B: exact 16-NN, G=4 threads/query, batch-16 sort --
// Selection is a uniform branch-free pipeline: per batch of 16 candidates,
// bitonic-sort the batch in registers (80 CE), then bitonic-merge into the
// running sorted top-16 (16 min + 32 CE). No data-dependent insert path, so
// no wave-divergence cost. Distance fma sequence bit-identical to the
// round-2 passing kernel. 4 partial lists merge via 2 shfl_xor bitonic
// stages; index recovery compacts via LDS atomic (order-free downstream).
__global__ __launch_bounds__(256) void k_knn(const float2* __restrict__ pos,
                                             int* __restrict__ idx)
{
    __shared__ float2 sp[N_];
    __shared__ int scnt[64];
    const int bt    = blockIdx.x >> 5;          // 32 blocks per bt
    const int qbase = (blockIdx.x & 31) << 6;   // 64 queries per block
    const float2* pb = pos + (size_t)bt * N_;
    for (int m = threadIdx.x; m < N_; m += 256) sp[m] = pb[m];
    if (threadIdx.x < 64) scnt[threadIdx.x] = 0;
    __syncthreads();

    const int q = threadIdx.x >> 2;
    const int g = threadIdx.x & 3;
    const int n = qbase + q;
    const float xn = sp[n].x, yn = sp[n].y;

    float bd[K_];
    #pragma unroll
    for (int i = 0; i < K_; ++i) bd[i] = 3.402823466e38f;

    // Pass 1: 512 candidates/thread in 32 batches of 16: m = 64*i + 4*j + g
    for (int i = 0; i < 32; ++i) {
        float d[16];
        #pragma unroll
        for (int j = 0; j < 16; ++j) {
            float2 p = sp[64*i + 4*j + g];
            float sps = __fmaf_rn(p.x, p.x, __fmul_rn(p.y, p.y));
            float t = __fmul_rn(xn, p.x);
            t = __fmaf_rn(yn, p.y, t);
            d[j] = __fmaf_rn(-2.f, t, sps);
        }
        // bitonic sort d[0..15] ascending (all indices compile-time)
        #pragma unroll
        for (int k = 2; k <= 16; k <<= 1) {
            #pragma unroll
            for (int jj = k >> 1; jj > 0; jj >>= 1) {
                #pragma unroll
                for (int ii = 0; ii < 16; ++ii) {
                    int ll = ii ^ jj;
                    if (ll > ii) {
                        float lo = fminf(d[ii], d[ll]);
                        float hi = fmaxf(d[ii], d[ll]);
                        if ((ii & k) == 0) { d[ii] = lo; d[ll] = hi; }
                        else               { d[ii] = hi; d[ll] = lo; }
                    }
                }
            }
        }
        // merge: keep lowest 16 of (bd asc) U (d asc); result asc
        #pragma unroll
        for (int ii = 0; ii < 16; ++ii) bd[ii] = fminf(bd[ii], d[15-ii]);
        #pragma unroll
        for (int jj = 8; jj > 0; jj >>= 1) {
            #pragma unroll
            for (int ii = 0; ii < 16; ++ii) {
                int ll = ii ^ jj;
                if (ll > ii) {
                    float lo = fminf(bd[ii], bd[ll]);
                    float hi = fmaxf(bd[ii], bd[ll]);
                    bd[ii] = lo; bd[ll] = hi;
                }
            }
        }
    }

    // Merge the 4 sorted lists across lanes: 2 stages of bitonic merge-16
    #pragma unroll
    for (int st = 1; st <= 2; st <<= 1) {
        float pr[K_];
        #pragma unroll
        for (int i = 0; i < K_; ++i) pr[i] = __shfl_xor(bd[K_-1-i], st, 64);
        #pragma unroll
        for (int i = 0; i < K_; ++i) bd[i] = fminf(bd[i], pr[i]);
        #pragma unroll
        for (int dd = 8; dd >= 1; dd >>= 1) {
            #pragma unroll
            for (int i = 0; i < K_; ++i) {
                if ((i & dd) == 0) {
                    float lo = fminf(bd[i], bd[i+dd]);
                    float hi = fmaxf(bd[i], bd[i+dd]);
                    bd[i] = lo; bd[i+dd] = hi;
                }
            }
        }
    }
    const float d15 = bd[K_-1];

    // Pass 2: recover indices (own stride only), compact via LDS atomic
    int* op = idx + ((size_t)bt * N_ + n) * K_;
    for (int i = 0; i < 64; ++i) {
        float d[8];
        #pragma unroll
        for (int j = 0; j < 8; ++j) {
            float2 p = sp[32*i + 4*j + g];
            float sps = __fmaf_rn(p.x, p.x, __fmul_rn(p.y, p.y));
            float t = __fmul_rn(xn, p.x);
            t = __fmaf_rn(yn, p.y, t);
            d[j] = __fmaf_rn(-2.f, t, sps);
        }
        float dm0 = fminf(fminf(d[0],d[1]), fminf(d[2],d[3]));
        float dm1 = fminf(fminf(d[4],d[5]), fminf(d[6],d[7]));
        if (fminf(dm0, dm1) <= d15) {
            #pragma unroll
            for (int j = 0; j < 8; ++j) {
                if (d[j] <= d15) {
                    int pos_ = atomicAdd(&scnt[q], 1);
                    if (pos_ < K_) op[pos_] = 32*i + 4*j + g;
                }
            }
        }
    }
}

// ---------------- Kernel C1: hw = h @ gat_W^T, s_self ----------------
__global__ __launch_bounds__(256) void k_gatw(
    const float* __restrict__ h, const float* __restrict__ gw,
    const float* __restrict__ att,
    float* __restrict__ hw, float* __restrict__ ssf)
{
    __shared__ float sw[D_*D_];
    __shared__ float sat[H_*HD_];
    int t = threadIdx.x;
    for (int i = t; i < D_*D_; i += 256) sw[i] = gw[i];
    if (t < H_*HD_) sat[t] = att[(t>>4)*(2*HD_) + (t & (HD_-1))];
    __syncthreads();

    int node = blockIdx.x * 256 + t;
    const float* hp = h + (size_t)node * D_;
    float hin[D_];
    #pragma unroll
    for (int j = 0; j < D_; j += 4) {
        float4 v = *(const float4*)(hp + j);
        hin[j] = v.x; hin[j+1] = v.y; hin[j+2] = v.z; hin[j+3] = v.w;
    }
    float* wp = hw + (size_t)node * D_;
    float ss[H_];
    #pragma unroll
    for (int hh = 0; hh < H_; ++hh) {
        ss[hh] = 0.f;
        #pragma unroll
        for (int jj = 0; jj < HD_; ++jj) {
            const int j = hh*HD_ + jj;
            float a = 0.f;
            const float4* wr = (const float4*)(&sw[j*D_]);
            #pragma unroll
            for (int c4 = 0; c4 < D_/4; ++c4) {
                float4 w4 = wr[c4];
                a = fmaf(hin[4*c4+0], w4.x, a);
                a = fmaf(hin[4*c4+1], w4.y, a);
                a = fmaf(hin[4*c4+2], w4.z, a);
                a = fmaf(hin[4*c4+3], w4.w, a);
            }
            wp[j] = a;
            ss[hh] = fmaf(a, sat[j], ss[hh]);
        }
    }
    float* sp2 = ssf + (size_t)node * H_;
    #pragma unroll
    for (int hh = 0; hh < H_; ++hh) sp2[hh] = ss[hh];
}

// ---------------- Kernel C2: GAT gather/softmax/aggregate + residual -------
__global__ __launch_bounds__(256) void k_gat(
    const float* __restrict__ hw, const float* __restrict__ ssf,
    const int* __restrict__ idx, const float* __restrict__ att,
    float* __restrict__ h /* in-out: becomes h_sp */)
{
    int t = threadIdx.x;
    int node = blockIdx.x * 64 + (t >> 2);
    int hh = t & 3;
    int bt = node >> 11;
    const int* ip = idx + (size_t)node * K_;

    float anb[HD_];
    #pragma unroll
    for (int i = 0; i < HD_; ++i) anb[i] = att[hh*(2*HD_) + HD_ + i];
    float ssv = ssf[(size_t)node*H_ + hh];
    const float* hwb = hw + ((size_t)bt * N_) * D_;

    int nb[K_];
    #pragma unroll
    for (int k = 0; k < K_; ++k) nb[k] = ip[k];

    float sc[K_];
    float mx = -3.402823466e38f;
    #pragma unroll
    for (int k = 0; k < K_; ++k) {
        const float* vp = hwb + (size_t)nb[k]*D_ + hh*HD_;
        float a = 0.f;
        #pragma unroll
        for (int i = 0; i < HD_; i += 4) {
            float4 v = *(const float4*)(vp + i);
            a = fmaf(v.x, anb[i],   a);
            a = fmaf(v.y, anb[i+1], a);
            a = fmaf(v.z, anb[i+2], a);
            a = fmaf(v.w, anb[i+3], a);
        }
        float s = ssv + a;
        s = (s >= 0.f) ? s : 0.2f * s;   // leaky_relu(0.2)
        sc[k] = s;
        mx = fmaxf(mx, s);
    }
    float den = 0.f;
    #pragma unroll
    for (int k = 0; k < K_; ++k) { sc[k] = __expf(sc[k] - mx); den += sc[k]; }
    float inv = 1.f / den;

    float acc[HD_];
    #pragma unroll
    for (int i = 0; i < HD_; ++i) acc[i] = 0.f;
    #pragma unroll
    for (int k = 0; k < K_; ++k) {
        float al = sc[k] * inv;
        const float* vp = hwb + (size_t)nb[k]*D_ + hh*HD_;
        #pragma unroll
        for (int i = 0; i < HD_; i += 4) {
            float4 v = *(const float4*)(vp + i);
            acc[i]   = fmaf(v.x, al, acc[i]);
            acc[i+1] = fmaf(v.y, al, acc[i+1]);
            acc[i+2] = fmaf(v.z, al, acc[i+2]);
            acc[i+3] = fmaf(v.w, al, acc[i+3]);
        }
    }
    float* hp = h + (size_t)node*D_ + hh*HD_;
    #pragma unroll
    for (int i = 0; i < HD_; ++i) hp[i] = fmaxf(acc[i] + hp[i], 0.f);
}

// ---------------- Kernel D1: Q and KV projections ----------------
__global__ __launch_bounds__(256) void k_qkv(
    const float* __restrict__ hsp,
    const float* __restrict__ qw, const float* __restrict__ qb,
    const float* __restrict__ kw, const float* __restrict__ kb,
    float* __restrict__ q, float* __restrict__ kv)
{
    __shared__ float s_qw[D_*D_], s_kw[D_*D_], s_qb[D_], s_kb[D_];
    int t = threadIdx.x;
    for (int i = t; i < D_*D_; i += 256) { s_qw[i] = qw[i]; s_kw[i] = kw[i]; }
    if (t < D_) { s_qb[t] = qb[t]; s_kb[t] = kb[t]; }
    __syncthreads();

    int r = blockIdx.x * 256 + t;
    const float* in; float* outp; const float* W; const float* bb;
    if (r < BT_*N_) {
        int bt = r >> 11; int n = r & (N_-1);
        int b = bt >> 2, tt = bt & 3;
        in = hsp + (size_t)r * D_;
        outp = kv + (((size_t)(b*N_ + n))*T_ + tt) * D_;
        W = s_kw; bb = s_kb;
    } else {
        int rr = r - BT_*N_;
        int b = rr >> 11, n = rr & (N_-1);
        in = hsp + ((size_t)(b*T_ + (T_-1))*N_ + n) * D_;
        outp = q + (size_t)rr * D_;
        W = s_qw; bb = s_qb;
    }
    float xin[D_];
    #pragma unroll
    for (int j = 0; j < D_; j += 4) {
        float4 v = *(const float4*)(in + j);
        xin[j] = v.x; xin[j+1] = v.y; xin[j+2] = v.z; xin[j+3] = v.w;
    }
    #pragma unroll 4
    for (int j = 0; j < D_; ++j) {
        float a = bb[j];
        const float4* wr = (const float4*)(&W[j*D_]);
        #pragma unroll
        for (int c4 = 0; c4 < D_/4; ++c4) {
            float4 w4 = wr[c4];
            a = fmaf(xin[4*c4+0], w4.x, a);
            a = fmaf(xin[4*c4+1], w4.y, a);
            a = fmaf(xin[4*c4+2], w4.z, a);
            a = fmaf(xin[4*c4+3], w4.w, a);
        }
        outp[j] = a;
    }
}

// ---------------- Kernel D2: temporal attention + output heads -------------
__global__ __launch_bounds__(64) void k_head(
    const float* __restrict__ q, const float* __restrict__ kv,
    const float* __restrict__ lw1, const float* __restrict__ lb1,
    const float* __restrict__ lw2, const float* __restrict__ lb2,
    const float* __restrict__ rw1, const float* __restrict__ rb1,
    const float* __restrict__ rw2, const float* __restrict__ rb2,
    float* __restrict__ out)
{
    __shared__ float sl1[32*D_], sr1[32*D_], sl2[4*32], sr2[4*32];
    __shared__ float slb1[32], srb1[32], slb2[4], srb2[4];
    int t = threadIdx.x;
    for (int i = t; i < 32*D_; i += 64) { sl1[i] = lw1[i]; sr1[i] = rw1[i]; }
    for (int i = t; i < 128; i += 64)   { sl2[i] = lw2[i]; sr2[i] = rw2[i]; }
    if (t < 32) { slb1[t] = lb1[t]; srb1[t] = rb1[t]; }
    if (t < 4)  { slb2[t] = lb2[t]; srb2[t] = rb2[t]; }
    __syncthreads();

    int rn = blockIdx.x * 64 + t;           // = b*N + n
    const float* qp = q + (size_t)rn * D_;
    const float* kp = kv + (size_t)rn * T_ * D_;

    float qv[D_];
    #pragma unroll
    for (int j = 0; j < D_; j += 4) {
        float4 v = *(const float4*)(qp + j);
        qv[j] = v.x; qv[j+1] = v.y; qv[j+2] = v.z; qv[j+3] = v.w;
    }
    float scv[T_];
    #pragma unroll
    for (int tt = 0; tt < T_; ++tt) {
        float a = 0.f;
        const float4* kr = (const float4*)(kp + tt*D_);
        #pragma unroll
        for (int c4 = 0; c4 < D_/4; ++c4) {
            float4 v = kr[c4];
            a = fmaf(qv[4*c4+0], v.x, a);
            a = fmaf(qv[4*c4+1], v.y, a);
            a = fmaf(qv[4*c4+2], v.z, a);
            a = fmaf(qv[4*c4+3], v.w, a);
        }
        scv[tt] = a * 0.125f;
    }
    float mx = fmaxf(fmaxf(scv[0], scv[1]), fmaxf(scv[2], scv[3]));
    float wsum = 0.f;
    #pragma unroll
    for (int tt = 0; tt < T_; ++tt) { scv[tt] = expf(scv[tt] - mx); wsum += scv[tt]; }
    float winv = 1.f / wsum;

    float hf[D_];
    #pragma unroll
    for (int j = 0; j < D_; ++j) hf[j] = 0.f;
    #pragma unroll
    for (int tt = 0; tt < T_; ++tt) {
        float w = scv[tt] * winv;
        const float4* kr = (const float4*)(kp + tt*D_);
        #pragma unroll
        for (int c4 = 0; c4 < D_/4; ++c4) {
            float4 v = kr[c4];
            hf[4*c4+0] = fmaf(v.x, w, hf[4*c4+0]);
            hf[4*c4+1] = fmaf(v.y, w, hf[4*c4+1]);
            hf[4*c4+2] = fmaf(v.z, w, hf[4*c4+2]);
            hf[4*c4+3] = fmaf(v.w, w, hf[4*c4+3]);
        }
    }
    // lidar head
    float ol0 = slb2[0], ol1 = slb2[1], ol2 = slb2[2], ol3 = slb2[3];
    #pragma unroll 2
    for (int j = 0; j < 32; ++j) {
        float a = slb1[j];
        const float4* wr = (const float4*)(&sl1[j*D_]);
        #pragma unroll
        for (int c4 = 0; c4 < D_/4; ++c4) {
            float4 v = wr[c4];
            a = fmaf(hf[4*c4+0], v.x, a);
            a = fmaf(hf[4*c4+1], v.y, a);
            a = fmaf(hf[4*c4+2], v.z, a);
            a = fmaf(hf[4*c4+3], v.w, a);
        }
        a = fmaxf(a, 0.f);
        ol0 = fmaf(a, sl2[0*32+j], ol0);
        ol1 = fmaf(a, sl2[1*32+j], ol1);
        ol2 = fmaf(a, sl2[2*32+j], ol2);
        ol3 = fmaf(a, sl2[3*32+j], ol3);
    }
    // radar head
    float or0 = srb2[0], or1 = srb2[1], or2 = srb2[2], or3 = srb2[3];
    #pragma unroll 2
    for (int j = 0; j < 32; ++j) {
        float a = srb1[j];
        const float4* wr = (const float4*)(&sr1[j*D_]);
        #pragma unroll
        for (int c4 = 0; c4 < D_/4; ++c4) {
            float4 v = wr[c4];
            a = fmaf(hf[4*c4+0], v.x, a);
            a = fmaf(hf[4*c4+1], v.y, a);
            a = fmaf(hf[4*c4+2], v.z, a);
            a = fmaf(hf[4*c4+3], v.w, a);
        }
        a = fmaxf(a, 0.f);
        or0 = fmaf(a, sr2[0*32+j], or0);
        or1 = fmaf(a, sr2[1*32+j], or1);
        or2 = fmaf(a, sr2[2*32+j], or2);
        or3 = fmaf(a, sr2[3*32+j], or3);
    }
    const int NB = B_ * N_;                  // 16384
    out[0*2*NB + rn*2 + 0] = ol0;
    out[0*2*NB + rn*2 + 1] = ol1;
    out[1*2*NB + rn*2 + 0] = softplus_f(ol2) + 1e-6f;
    out[1*2*NB + rn*2 + 1] = softplus_f(ol3) + 1e-6f;
    out[2*2*NB + rn*2 + 0] = or0;
    out[2*2*NB + rn*2 + 1] = or1;
    out[3*2*NB + rn*2 + 0] = softplus_f(or2) + 1e-6f;
    out[3*2*NB + rn*2 + 1] = softplus_f(or3) + 1e-6f;
}

// ---------------- launcher ----------------
extern "C" void kernel_launch(void* const* d_in, const int* in_sizes, int n_in,
                              void* d_out, int out_size, void* d_ws, size_t ws_size,
                              hipStream_t stream)
{
    const float* x   = (const float*)d_in[0];
    const float* ew1 = (const float*)d_in[1];
    const float* eb1 = (const float*)d_in[2];
    const float* g1  = (const float*)d_in[3];
    const float* bb1 = (const float*)d_in[4];
    const float* m1  = (const float*)d_in[5];
    const float* v1  = (const float*)d_in[6];
    const float* ew2 = (const float*)d_in[7];
    const float* eb2 = (const float*)d_in[8];
    const float* g2  = (const float*)d_in[9];
    const float* bb2 = (const float*)d_in[10];
    const float* m2  = (const float*)d_in[11];
    const float* v2  = (const float*)d_in[12];
    const float* gw  = (const float*)d_in[13];
    const float* att = (const float*)d_in[14];
    const float* qw  = (const float*)d_in[15];
    const float* qb  = (const float*)d_in[16];
    const float* kw  = (const float*)d_in[17];
    const float* kb  = (const float*)d_in[18];
    const float* lw1 = (const float*)d_in[19];
    const float* lb1 = (const float*)d_in[20];
    const float* lw2 = (const float*)d_in[21];
    const float* lb2 = (const float*)d_in[22];
    const float* rw1 = (const float*)d_in[23];
    const float* rb1 = (const float*)d_in[24];
    const float* rw2 = (const float*)d_in[25];
    const float* rb2 = (const float*)d_in[26];
    float* out = (float*)d_out;

    float* h   = (float*)d_ws;                               // BT*N*64
    float* hw  = h   + (size_t)BT_*N_*D_;                    // BT*N*64
    float* ssf = hw  + (size_t)BT_*N_*D_;                    // BT*N*4
    int*   idx = (int*)(ssf + (size_t)BT_*N_*H_);            // BT*N*16
    float* q   = (float*)(idx + (size_t)BT_*N_*K_);          // B*N*64
    float* kv  = hw;             // reuse hw after GAT aggregation
    float2* pos = (float2*)q;    // overlap: pos dead before k_qkv writes q

    k_embed<<<BT_*N_/256, 256, 0, stream>>>(x, ew1, eb1, g1, bb1, m1, v1,
                                            ew2, eb2, g2, bb2, m2, v2, h, pos);
    k_knn<<<BT_*(N_/64), 256, 0, stream>>>(pos, idx);
    k_gatw<<<BT_*N_/256, 256, 0, stream>>>(h, gw, att, hw, ssf);
    k_gat<<<(BT_*N_*H_)/256, 256, 0, stream>>>(hw, ssf, idx, att, h);
    k_qkv<<<(BT_*N_ + B_*N_)/256, 256, 0, stream>>>(h, qw, qb, kw, kb, q, kv);
    k_head<<<(B_*N_)/64, 64, 0, stream>>>(q, kv, lw1, lb1, lw2, lb2,
                                          rw1, rb1, rw2, rb2, out);
}